// Round 18
// baseline (653.034 us; speedup 1.0000x reference)
//
#include <hip/hip_runtime.h>

typedef __attribute__((ext_vector_type(8))) short bf16x8;
typedef __attribute__((ext_vector_type(4))) float f32x4;
typedef unsigned short ushort_t;
typedef unsigned int uint32;

#define DEV __device__ __forceinline__
#define SBAR() __builtin_amdgcn_sched_barrier(0)

// round-to-nearest-even f32 -> bf16 (bits)
DEV ushort_t f2bf(float f) {
    uint32 u = __float_as_uint(f);
    uint32 r = (u + 0x7FFFu + ((u >> 16) & 1u)) >> 16;
    return (ushort_t)r;
}
DEV float bf2f(ushort_t h) { return __uint_as_float(((uint32)h) << 16); }

#define MFMA16(a, b, c) __builtin_amdgcn_mfma_f32_16x16x32_bf16((a), (b), (c), 0, 0, 0)

DEV void gload_lds16(const void* g, void* l) {
    __builtin_amdgcn_global_load_lds((const __attribute__((address_space(1))) void*)g,
                                     (__attribute__((address_space(3))) void*)l,
                                     16, 0, 0);
}

// ---------------------------------------------------------------------------
// init: f32 x -> bf16 residual stream xr
// ---------------------------------------------------------------------------
__global__ __launch_bounds__(256) void init_x(const float* __restrict__ xin,
                                              ushort_t* __restrict__ xr, int n4) {
    int i = blockIdx.x * 256 + threadIdx.x;
    if (i >= n4) return;
    float4 v = ((const float4*)xin)[i];
    ushort4 h;
    h.x = f2bf(v.x); h.y = f2bf(v.y); h.z = f2bf(v.z); h.w = f2bf(v.w);
    ((ushort4*)xr)[i] = h;
}

// ---------------------------------------------------------------------------
// all weight transposes in ONE launch: src (K x N f32) -> dst (N x K bf16).
// ---------------------------------------------------------------------------
__global__ __launch_bounds__(256) void transpose_all(const float* __restrict__ Wq,
                                                     const float* __restrict__ Wk,
                                                     const float* __restrict__ Wv,
                                                     const float* __restrict__ Wo,
                                                     const float* __restrict__ W1,
                                                     const float* __restrict__ W2,
                                                     ushort_t* __restrict__ wqkvT,
                                                     ushort_t* __restrict__ woT,
                                                     ushort_t* __restrict__ w1T,
                                                     ushort_t* __restrict__ w2T) {
    const int l = blockIdx.y;
    const int t = blockIdx.x;
    const float* src;
    ushort_t* dst;
    int K, N, ktile, ntile;
    if (t < 4096) {
        const int which = t >> 10, tile = t & 1023;
        K = 1024; N = 1024; ktile = tile >> 5; ntile = tile & 31;
        const size_t o1 = (size_t)l * 1048576;
        if (which == 0)      { src = Wq + o1; dst = wqkvT + (size_t)l * 3145728; }
        else if (which == 1) { src = Wk + o1; dst = wqkvT + (size_t)l * 3145728 + 1048576; }
        else if (which == 2) { src = Wv + o1; dst = wqkvT + (size_t)l * 3145728 + 2097152; }
        else                 { src = Wo + o1; dst = woT + o1; }
    } else if (t < 8192) {
        const int tile = t - 4096;
        K = 1024; N = 4096; ktile = tile >> 7; ntile = tile & 127;
        src = W1 + (size_t)l * 4194304; dst = w1T + (size_t)l * 4194304;
    } else {
        const int tile = t - 8192;
        K = 4096; N = 1024; ktile = tile >> 5; ntile = tile & 31;
        src = W2 + (size_t)l * 4194304; dst = w2T + (size_t)l * 4194304;
    }
    __shared__ float tilebuf[32][33];
    const int tx = threadIdx.x, ty = threadIdx.y;  // (32,8)
    const int nt = ntile * 32, kt = ktile * 32;
#pragma unroll
    for (int j = 0; j < 4; ++j)
        tilebuf[ty + j * 8][tx] = src[(size_t)(kt + ty + j * 8) * N + nt + tx];
    __syncthreads();
#pragma unroll
    for (int j = 0; j < 4; ++j)
        dst[(size_t)(nt + ty + j * 8) * K + kt + tx] = f2bf(tilebuf[tx][ty + j * 8]);
}

// ---------------------------------------------------------------------------
// GEMM: C[M,N] = A[M,K] @ BT[N,K]^T + bias. BM x 256 tile, 8 waves (2M x 4N).
// BK=64: verified r11/r14 schedule (PHASES: BM=256 -> 4, BM=128 -> 2;
//   (mi-half x ks) slicing, counted vmcnt(4) at t+2 depth).
// BK=32: 2 phases/K-tile, verified slot discipline (stage A(t+1)@p0 -> nb,
//   B(t+2)@p1 -> cb + vmcnt(2)). For BM=256 this halves LDS (64KB -> 2
//   blocks/CU TLP) at the SAME barrier count per unit K as BK=64/4-phase.
// WAR-safety note (r13/r16 lessons): the conflicting B(t+2) stage must sit in
// a NARROW phase — merged phases exceed the ~200cy write-back margin (race).
// Do not merge phases or defer reads past MFMA.
// MODE: 1 = bf16 out (+RELU), 2 = fused QKV split.
// ---------------------------------------------------------------------------
template <int BM, int BK, int MODE, int RELU>
__global__ __launch_bounds__(512, 2) void gemm8p(const ushort_t* __restrict__ A,
                                                 const ushort_t* __restrict__ BT,
                                                 const float* __restrict__ bias,
                                                 void* __restrict__ Cout,
                                                 int M, int N, int K, int gx,
                                                 ushort_t* __restrict__ qout,
                                                 ushort_t* __restrict__ kout,
                                                 ushort_t* __restrict__ vtout,
                                                 const float* __restrict__ bq,
                                                 const float* __restrict__ bk,
                                                 const float* __restrict__ bv) {
    constexpr int AH = BM / 128;
    constexpr int MREP = BM / 32;
    constexpr int MH = MREP / 2;
    constexpr int PHASES = (BM == 128) ? 2 : 4;   // BK=64 path only
    constexpr int BUFSZ = (BM + 256) * BK;
    constexpr int LDSSZ = (MODE == 2 && 2 * BUFSZ < 32768) ? 32768 : 2 * BUFSZ;
    constexpr int HALF = 128 * BK;                // elems per 128-row half
    __shared__ ushort_t ldsf[LDSSZ];

    // XCD-aware bijective swizzle (m204) + 8-row grouped tile order (gy%8==0)
    const int nwg = gridDim.x;
    const int q8 = nwg >> 3, r8 = nwg & 7;
    const int xcd = blockIdx.x & 7, idx = blockIdx.x >> 3;
    const int swz = (xcd < r8 ? xcd * (q8 + 1) : r8 * (q8 + 1) + (xcd - r8) * q8) + idx;
    const int gchunk = gx * 8;
    const int grp = swz / gchunk, rem = swz % gchunk;
    const int byi = grp * 8 + (rem & 7);
    const int bxi = rem >> 3;

    const int tid = threadIdx.x;
    const int w = tid >> 6, lane = tid & 63;
    const int wr = w >> 2, wc = w & 3;
    const int lr = lane & 15, lh = lane >> 4;
    const int row0 = byi * BM, col0 = bxi * 256;

    f32x4 acc[MREP][4] = {};

    const ushort_t* __restrict__ Ab = A + (size_t)row0 * K;
    const ushort_t* __restrict__ Bb = BT + (size_t)col0 * K;
    const int nt = K / BK;

    // staging geometry
    const int r8l = lane >> 3;                    // BK=64: row-in-8 block
    const int cu64 = (lane & 7) ^ r8l;            // BK=64 swizzled col unit
    const int so64 = w * 1024 + lane * 8;         // BK=64 dest elems
    const int srow32 = tid >> 2;                  // BK=32: row 0..127
    const int cu32 = (tid & 3) ^ ((srow32 >> 1) & 3);  // BK=32 swizzled unit

    const ushort_t* aS[AH][2];
    const ushort_t* bS[2][2];
#pragma unroll
    for (int h2 = 0; h2 < AH; ++h2)
#pragma unroll
        for (int i = 0; i < 2; ++i) {
            if (BK == 64)
                aS[h2][i] = Ab + (size_t)(h2 * 128 + (w * 2 + i) * 8 + r8l) * K + cu64 * 8;
            else
                aS[h2][i] = Ab + (size_t)(h2 * 128 + srow32) * K + cu32 * 8;
        }
#pragma unroll
    for (int h2 = 0; h2 < 2; ++h2)
#pragma unroll
        for (int i = 0; i < 2; ++i) {
            if (BK == 64)
                bS[h2][i] = Bb + (size_t)(h2 * 128 + (w * 2 + i) * 8 + r8l) * K + cu64 * 8;
            else
                bS[h2][i] = Bb + (size_t)(h2 * 128 + srow32) * K + cu32 * 8;
        }

    auto stageA = [&](int buf, int h2) {
        if (BK == 64) {
#pragma unroll
            for (int i = 0; i < 2; ++i) {
                gload_lds16(aS[h2][i], &ldsf[buf * BUFSZ + h2 * HALF + so64 + i * 512]);
                aS[h2][i] += 64;
            }
        } else {
            gload_lds16(aS[h2][0], &ldsf[buf * BUFSZ + h2 * HALF + tid * 8]);
            aS[h2][0] += 32;
        }
    };
    auto stageB = [&](int buf, int h2) {
        if (BK == 64) {
#pragma unroll
            for (int i = 0; i < 2; ++i) {
                gload_lds16(bS[h2][i], &ldsf[buf * BUFSZ + BM * BK + h2 * HALF + so64 + i * 512]);
                bS[h2][i] += 64;
            }
        } else {
            gload_lds16(bS[h2][0], &ldsf[buf * BUFSZ + BM * BK + h2 * HALF + tid * 8]);
            bS[h2][0] += 32;
        }
    };

    int boff[4][2];
#pragma unroll
    for (int ni = 0; ni < 4; ++ni) {
        const int br = wc * 64 + ni * 16 + lr;
        const int rr = br & 127, bh2 = br >> 7;
#pragma unroll
        for (int ks = 0; ks < 2; ++ks) {
            if (BK == 64)
                boff[ni][ks] = BM * 64 + bh2 * HALF + rr * 64 + (((ks * 4 + lh) ^ (rr & 7)) * 8);
            else
                boff[ni][ks] = BM * 32 + bh2 * HALF + rr * 32 + ((lh ^ ((rr >> 1) & 3)) * 8);
        }
    }
    int aoff[MREP][2];
#pragma unroll
    for (int mi = 0; mi < MREP; ++mi) {
        const int fr = wr * (BM / 2) + mi * 16 + lr;
        const int rr = fr & 127, fh = fr >> 7;
#pragma unroll
        for (int ks = 0; ks < 2; ++ks) {
            if (BK == 64)
                aoff[mi][ks] = fh * HALF + rr * 64 + (((ks * 4 + lh) ^ (rr & 7)) * 8);
            else
                aoff[mi][ks] = fh * HALF + rr * 32 + ((lh ^ ((rr >> 1) & 3)) * 8);
        }
    }

    // prologue: tile0 B+A, tile1 B; counted wait completes tile 0
    stageB(0, 0); stageB(0, 1);
    stageA(0, 0); if (AH == 2) stageA(0, 1);
    stageB(1, 0); stageB(1, 1);
    if (BK == 64) asm volatile("s_waitcnt vmcnt(4)" ::: "memory");
    else          asm volatile("s_waitcnt vmcnt(2)" ::: "memory");
    SBAR();
    __builtin_amdgcn_s_barrier();

    for (int t2 = 0; t2 < nt; t2 += 2) {
#pragma unroll
        for (int ti = 0; ti < 2; ++ti) {
            const int t = t2 + ti;
            if (BK == 64) {
                // ------- verified r11/r14 BK=64 path -------
                bf16x8 bfr[2][4];
#pragma unroll
                for (int p = 0; p < PHASES; ++p) {
                    const int ks = p & 1;
                    const int mh = (PHASES == 4) ? (p >> 1) : 0;
                    if (mh == 0) {
#pragma unroll
                        for (int ni = 0; ni < 4; ++ni)
                            bfr[ks][ni] = *(const bf16x8*)&ldsf[ti * BUFSZ + boff[ni][ks]];
                    }
                    bf16x8 af[4];
#pragma unroll
                    for (int mm = 0; mm < 4; ++mm)
                        af[mm] = *(const bf16x8*)&ldsf[ti * BUFSZ + aoff[mh * 4 + mm][ks]];
                    if (PHASES == 4) {
                        if (p == 0) { if (t + 1 < nt) stageA(1 - ti, 0); }
                        else if (p == 1) { if (AH == 2 && t + 1 < nt) stageA(1 - ti, 1); }
                        else if (p == 2) { if (t + 2 < nt) stageB(ti, 0); }
                        else {
                            if (t + 2 < nt) {
                                stageB(ti, 1);
                                asm volatile("s_waitcnt vmcnt(4)" ::: "memory");
                            } else if (t + 1 < nt) {
                                asm volatile("s_waitcnt vmcnt(0)" ::: "memory");
                            }
                        }
                    } else {
                        if (p == 0) { if (t + 1 < nt) stageA(1 - ti, 0); }
                        else {
                            if (t + 2 < nt) {
                                stageB(ti, 0);
                                stageB(ti, 1);
                                asm volatile("s_waitcnt vmcnt(4)" ::: "memory");
                            } else if (t + 1 < nt) {
                                asm volatile("s_waitcnt vmcnt(0)" ::: "memory");
                            }
                        }
                    }
                    SBAR();
                    __builtin_amdgcn_s_barrier();
                    asm volatile("s_waitcnt lgkmcnt(0)" ::: "memory");
                    SBAR();
                    __builtin_amdgcn_s_setprio(1);
#pragma unroll
                    for (int mm = 0; mm < 4; ++mm)
#pragma unroll
                        for (int ni = 0; ni < 4; ++ni)
                            acc[mh * 4 + mm][ni] = MFMA16(af[mm], bfr[ks][ni], acc[mh * 4 + mm][ni]);
                    __builtin_amdgcn_s_setprio(0);
                    SBAR();
                    __builtin_amdgcn_s_barrier();
                }
            } else {
                // ------- BK=32 path (2 phases, verified slot discipline) -------
                bf16x8 bfr[4], af[MREP];
                // p0: read B + A[0..MH-1]; stage A(t+1)->nb
#pragma unroll
                for (int ni = 0; ni < 4; ++ni)
                    bfr[ni] = *(const bf16x8*)&ldsf[ti * BUFSZ + boff[ni][0]];
#pragma unroll
                for (int mi = 0; mi < MH; ++mi)
                    af[mi] = *(const bf16x8*)&ldsf[ti * BUFSZ + aoff[mi][0]];
                if (t + 1 < nt) {
                    stageA(1 - ti, 0);
                    if (AH == 2) stageA(1 - ti, 1);
                }
                SBAR();
                __builtin_amdgcn_s_barrier();
                asm volatile("s_waitcnt lgkmcnt(0)" ::: "memory");
                SBAR();
                __builtin_amdgcn_s_setprio(1);
#pragma unroll
                for (int mi = 0; mi < MH; ++mi)
#pragma unroll
                    for (int ni = 0; ni < 4; ++ni)
                        acc[mi][ni] = MFMA16(af[mi], bfr[ni], acc[mi][ni]);
                __builtin_amdgcn_s_setprio(0);
                SBAR();
                __builtin_amdgcn_s_barrier();
                // p1: read A[MH..]; stage B(t+2)->cb + vmcnt(2)
#pragma unroll
                for (int mi = MH; mi < MREP; ++mi)
                    af[mi] = *(const bf16x8*)&ldsf[ti * BUFSZ + aoff[mi][0]];
                if (t + 2 < nt) {
                    stageB(ti, 0);
                    stageB(ti, 1);
                    asm volatile("s_waitcnt vmcnt(2)" ::: "memory");
                } else if (t + 1 < nt) {
                    asm volatile("s_waitcnt vmcnt(0)" ::: "memory");
                }
                SBAR();
                __builtin_amdgcn_s_barrier();
                asm volatile("s_waitcnt lgkmcnt(0)" ::: "memory");
                SBAR();
                __builtin_amdgcn_s_setprio(1);
#pragma unroll
                for (int mi = MH; mi < MREP; ++mi)
#pragma unroll
                    for (int ni = 0; ni < 4; ++ni)
                        acc[mi][ni] = MFMA16(af[mi], bfr[ni], acc[mi][ni]);
                __builtin_amdgcn_s_setprio(0);
                SBAR();
                __builtin_amdgcn_s_barrier();
            }
        }
    }
    (void)M;

    // ---------------- epilogue ----------------
    if (MODE == 2 && col0 >= 2048) {
        ushort_t* vb = ldsf + w * 4096;
        const int hglob = (col0 - 2048 + wc * 64) >> 6;
        const int bidx = row0 >> 10;
        const int srow0 = (row0 & 1023) + wr * 64;
#pragma unroll
        for (int mi = 0; mi < MREP; ++mi) {
#pragma unroll
            for (int ni = 0; ni < 4; ++ni) {
                const int dd = ni * 16 + lr;
                const float bvv = bv[(hglob << 6) + dd];
                ushort4 h4;
                h4.x = f2bf(acc[mi][ni][0] + bvv);
                h4.y = f2bf(acc[mi][ni][1] + bvv);
                h4.z = f2bf(acc[mi][ni][2] + bvv);
                h4.w = f2bf(acc[mi][ni][3] + bvv);
                const int sb = mi * 32 + lh * 8;
                *(ushort4*)((char*)vb + dd * 128 + (sb ^ ((dd & 3) << 4))) = h4;
            }
        }
        const int ddl = lane >> 3, s8 = lane & 7;
#pragma unroll
        for (int j = 0; j < 8; ++j) {
            const int dd = j * 8 + ddl;
            bf16x8 rowv = *(const bf16x8*)((char*)vb + dd * 128 + ((s8 * 16) ^ ((dd & 3) << 4)));
            *(bf16x8*)&vtout[(((size_t)(bidx * 16 + hglob) * 64 + dd) << 10) + srow0 + s8 * 8] = rowv;
        }
    } else {
#pragma unroll
        for (int mi = 0; mi < MREP; ++mi) {
#pragma unroll
            for (int ni = 0; ni < 4; ++ni) {
                const int col = col0 + wc * 64 + ni * 16 + lr;
                const int rowb = row0 + wr * (BM / 2) + mi * 16 + lh * 4;
                if (MODE == 2) {
                    if (col < 1024) {
                        const float bvv = bq[col];
#pragma unroll
                        for (int r = 0; r < 4; ++r)
                            qout[(size_t)(rowb + r) * 1024 + col] = f2bf((acc[mi][ni][r] + bvv) * 0.125f);
                    } else {
                        const int c = col - 1024;
                        const float bvv = bk[c];
#pragma unroll
                        for (int r = 0; r < 4; ++r)
                            kout[(size_t)(rowb + r) * 1024 + c] = f2bf(acc[mi][ni][r] + bvv);
                    }
                } else {
                    const float bvv = bias[col];
#pragma unroll
                    for (int r = 0; r < 4; ++r) {
                        float val = acc[mi][ni][r] + bvv;
                        if (RELU) val = fmaxf(val, 0.f);
                        ((ushort_t*)Cout)[(size_t)(rowb + r) * N + col] = f2bf(val);
                    }
                }
            }
        }
    }
}

// ---------------------------------------------------------------------------
// fused causal flash attention, KVBLK=128. Grid (bh=128, qt=16).
// ---------------------------------------------------------------------------
__global__ __launch_bounds__(256) void attn_kernel(const ushort_t* __restrict__ q,
                                                   const ushort_t* __restrict__ k,
                                                   const ushort_t* __restrict__ vt,
                                                   ushort_t* __restrict__ o) {
    __shared__ ushort_t ktile[128 * 64];     // 16KB
    __shared__ ushort_t vtile[64 * 128];     // 16KB (dh x 128 keys)
    __shared__ ushort_t p_lds[4][16 * 128];  // 16KB per-wave P

    const int bh = blockIdx.x;
    const int b = bh >> 4, h = bh & 15;
    const int qt = blockIdx.y;
    const int tid = threadIdx.x, w = tid >> 6, lane = tid & 63;
    const int lr = lane & 15, lh = lane >> 4;
    const int qbase = qt * 64 + w * 16;
    const size_t headoff = (size_t)b * 1024 * 1024 + h * 64;
    const size_t vhead = (size_t)(b * 16 + h) << 16;

    bf16x8 qf[2];
#pragma unroll
    for (int ks = 0; ks < 2; ++ks)
        qf[ks] = *(const bf16x8*)&q[headoff + (size_t)(qbase + lr) * 1024 + ks * 32 + lh * 8];

    f32x4 oacc[4] = {};
    float m[4] = {-INFINITY, -INFINITY, -INFINITY, -INFINITY};
    float ls[4] = {0.f, 0.f, 0.f, 0.f};

    const int srow = tid >> 3;
    const int scol8 = (tid & 7) * 8;
    char* const kbase = (char*)ktile;
    char* const vbase = (char*)vtile;
    const int kswzb = (scol8 * 2) ^ ((srow & 7) << 4);
    const int vswzr = ((srow & 15) << 4);
    const ushort_t* kg = k + headoff + (size_t)srow * 1024 + scol8;
    const ushort_t* vg = vt + vhead + (size_t)srow * 1024 + scol8;

    const int jmaxw = qbase + 15;
    const int jend = qt * 64 + 63;

    bf16x8 sk[4], sv[4];
#pragma unroll
    for (int p = 0; p < 4; ++p) sk[p] = *(const bf16x8*)&kg[(size_t)(p * 32) * 1024];
#pragma unroll
    for (int p = 0; p < 2; ++p)
#pragma unroll
        for (int kh = 0; kh < 2; ++kh)
            sv[p * 2 + kh] = *(const bf16x8*)&vg[(size_t)(p * 32) * 1024 + kh * 64];

    for (int j0 = 0; j0 <= jend; j0 += 128) {
        __syncthreads();
#pragma unroll
        for (int p = 0; p < 4; ++p)
            *(bf16x8*)(kbase + (srow + 32 * p) * 128 + kswzb) = sk[p];
#pragma unroll
        for (int p = 0; p < 2; ++p)
#pragma unroll
            for (int kh = 0; kh < 2; ++kh)
                *(bf16x8*)(vbase + (srow + 32 * p) * 256 + ((kh * 128 + scol8 * 2) ^ vswzr)) = sv[p * 2 + kh];
        __syncthreads();
        if (j0 + 128 <= jend) {
#pragma unroll
            for (int p = 0; p < 4; ++p)
                sk[p] = *(const bf16x8*)&kg[(size_t)(j0 + 128 + p * 32) * 1024];
#pragma unroll
            for (int p = 0; p < 2; ++p)
#pragma unroll
                for (int kh = 0; kh < 2; ++kh)
                    sv[p * 2 + kh] = *(const bf16x8*)&vg[(size_t)(p * 32) * 1024 + j0 + 128 + kh * 64];
        }

        if (j0 <= jmaxw) {
            f32x4 s[8] = {};
#pragma unroll
            for (int kt = 0; kt < 8; ++kt) {
                const int krow = kt * 16 + lr;
                const int rswz = ((krow & 7) << 4);
#pragma unroll
                for (int ks = 0; ks < 2; ++ks) {
                    bf16x8 kf = *(const bf16x8*)(kbase + krow * 128 + ((ks * 64 + lh * 16) ^ rswz));
                    s[kt] = MFMA16(qf[ks], kf, s[kt]);
                }
            }
            if (j0 + 127 > qbase) {
#pragma unroll
                for (int kt = 0; kt < 8; ++kt)
#pragma unroll
                    for (int r = 0; r < 4; ++r)
                        s[kt][r] = ((j0 + kt * 16 + lr) <= (qbase + lh * 4 + r)) ? s[kt][r] : -1e9f;
            }
#pragma unroll
            for (int r = 0; r < 4; ++r) {
                float pm = fmaxf(fmaxf(fmaxf(s[0][r], s[1][r]), fmaxf(s[2][r], s[3][r])),
                                 fmaxf(fmaxf(s[4][r], s[5][r]), fmaxf(s[6][r], s[7][r])));
                pm = fmaxf(pm, __shfl_xor(pm, 1, 16));
                pm = fmaxf(pm, __shfl_xor(pm, 2, 16));
                pm = fmaxf(pm, __shfl_xor(pm, 4, 16));
                pm = fmaxf(pm, __shfl_xor(pm, 8, 16));
                const float mn = fmaxf(m[r], pm);
                const float corr = __expf(m[r] - mn);
                m[r] = mn;
                float ps = 0.f;
#pragma unroll
                for (int kt = 0; kt < 8; ++kt) {
                    const float pv = __expf(s[kt][r] - mn);
                    s[kt][r] = pv;
                    ps += pv;
                }
                ps += __shfl_xor(ps, 1, 16);
                ps += __shfl_xor(ps, 2, 16);
                ps += __shfl_xor(ps, 4, 16);
                ps += __shfl_xor(ps, 8, 16);
                ls[r] = ls[r] * corr + ps;
                oacc[0][r] *= corr; oacc[1][r] *= corr;
                oacc[2][r] *= corr; oacc[3][r] *= corr;
            }
            char* const pb = (char*)p_lds[w];
#pragma unroll
            for (int r = 0; r < 4; ++r) {
                const int qrow = lh * 4 + r;
                const int qswz = ((qrow & 15) << 4);
#pragma unroll
                for (int kt = 0; kt < 8; ++kt)
                    *(ushort_t*)(pb + qrow * 256 + ((kt * 32 + lr * 2) ^ qswz)) = f2bf(s[kt][r]);
            }
            const int pswz = ((lr & 15) << 4);
            bf16x8 pa[4];
#pragma unroll
            for (int ks = 0; ks < 4; ++ks)
                pa[ks] = *(const bf16x8*)(pb + lr * 256 + ((ks * 64 + lh * 16) ^ pswz));
#pragma unroll
            for (int dt = 0; dt < 4; ++dt) {
                const int vrow = dt * 16 + lr;
                const int vswz = ((vrow & 15) << 4);
#pragma unroll
                for (int ks = 0; ks < 4; ++ks) {
                    bf16x8 vf = *(const bf16x8*)(vbase + vrow * 256 + ((ks * 64 + lh * 16) ^ vswz));
                    oacc[dt] = MFMA16(pa[ks], vf, oacc[dt]);
                }
            }
        }
    }

    float inv[4];
#pragma unroll
    for (int r = 0; r < 4; ++r) inv[r] = 1.f / ls[r];
#pragma unroll
    for (int dt = 0; dt < 4; ++dt)
#pragma unroll
        for (int r = 0; r < 4; ++r) {
            const int row = qbase + lh * 4 + r;
            o[headoff + (size_t)row * 1024 + dt * 16 + lr] = f2bf(oacc[dt][r] * inv[r]);
        }
}

// ---------------------------------------------------------------------------
// fused residual + LayerNorm on bf16 residual stream: y = LN(t + xr).
// LAST=0: xr <- bf16(y).  LAST=1: out (f32, d_out) <- y.
// ---------------------------------------------------------------------------
template <int LAST>
__global__ __launch_bounds__(256) void add_ln(const ushort_t* __restrict__ t,
                                              ushort_t* __restrict__ xr,
                                              const float* __restrict__ g,
                                              const float* __restrict__ bb,
                                              float* __restrict__ out) {
    const int row = blockIdx.x, tid = threadIdx.x;
    const int lane = tid & 63, w = tid >> 6;
    const size_t base = (size_t)row * 1024;
    ushort4 tv = ((const ushort4*)(t + base))[tid];
    ushort4 xv = ((const ushort4*)(xr + base))[tid];
    float v0 = bf2f(tv.x) + bf2f(xv.x), v1 = bf2f(tv.y) + bf2f(xv.y);
    float v2 = bf2f(tv.z) + bf2f(xv.z), v3 = bf2f(tv.w) + bf2f(xv.w);
    float s = v0 + v1 + v2 + v3;
    float sq = v0 * v0 + v1 * v1 + v2 * v2 + v3 * v3;
#pragma unroll
    for (int off = 32; off >= 1; off >>= 1) {
        s += __shfl_xor(s, off);
        sq += __shfl_xor(sq, off);
    }
    __shared__ float red[8];
    if (lane == 0) { red[w] = s; red[4 + w] = sq; }
    __syncthreads();
    s = red[0] + red[1] + red[2] + red[3];
    sq = red[4] + red[5] + red[6] + red[7];
    const float mu = s * (1.f / 1024.f);
    const float var = sq * (1.f / 1024.f) - mu * mu;
    const float rs = rsqrtf(var + 1e-6f);
    float4 gv = ((const float4*)g)[tid];
    float4 bv = ((const float4*)bb)[tid];
    float y0 = (v0 - mu) * rs * gv.x + bv.x;
    float y1 = (v1 - mu) * rs * gv.y + bv.y;
    float y2 = (v2 - mu) * rs * gv.z + bv.z;
    float y3 = (v3 - mu) * rs * gv.w + bv.w;
    if (LAST) {
        float4 yo; yo.x = y0; yo.y = y1; yo.z = y2; yo.w = y3;
        ((float4*)(out + base))[tid] = yo;
    } else {
        ushort4 hh;
        hh.x = f2bf(y0); hh.y = f2bf(y1); hh.z = f2bf(y2); hh.w = f2bf(y3);
        ((ushort4*)(xr + base))[tid] = hh;
    }
}

// ---------------------------------------------------------------------------
extern "C" void kernel_launch(void* const* d_in, const int* in_sizes, int n_in,
                              void* d_out, int out_size, void* d_ws, size_t ws_size,
                              hipStream_t stream) {
    (void)in_sizes; (void)n_in; (void)out_size; (void)ws_size;
    const int B = 8, S = 1024, D = 1024, DFF = 4096, L = 2;
    const int M = B * S;  // 8192

    const float* x_in = (const float*)d_in[0];
    const float* Wq = (const float*)d_in[2];
    const float* bq = (const float*)d_in[3];
    const float* Wk = (const float*)d_in[4];
    const float* bk = (const float*)d_in[5];
    const float* Wv = (const float*)d_in[6];
    const float* bv = (const float*)d_in[7];
    const float* Wo = (const float*)d_in[8];
    const float* bo = (const float*)d_in[9];
    const float* W1 = (const float*)d_in[10];
    const float* b1 = (const float*)d_in[11];
    const float* W2 = (const float*)d_in[12];
    const float* b2 = (const float*)d_in[13];
    const float* ln1g = (const float*)d_in[14];
    const float* ln1b = (const float*)d_in[15];
    const float* ln2g = (const float*)d_in[16];
    const float* ln2b = (const float*)d_in[17];

    float* out = (float*)d_out;
    char* ws = (char*)d_ws;
    const size_t MB = 1024 * 1024;
    ushort_t* wqkvT = (ushort_t*)(ws + 0 * MB);
    ushort_t* woT = (ushort_t*)(ws + 12 * MB);
    ushort_t* w1T = (ushort_t*)(ws + 16 * MB);
    ushort_t* w2T = (ushort_t*)(ws + 32 * MB);
    ushort_t* xr  = (ushort_t*)(ws + 48 * MB);
    ushort_t* qb  = (ushort_t*)(ws + 64 * MB);
    ushort_t* kb  = (ushort_t*)(ws + 80 * MB);
    ushort_t* vtb = (ushort_t*)(ws + 96 * MB);
    ushort_t* ob  = (ushort_t*)(ws + 112 * MB);
    ushort_t* hb  = (ushort_t*)(ws + 64 * MB);
    ushort_t* tb  = (ushort_t*)(ws + 128 * MB);

    init_x<<<M * D / 4 / 256, 256, 0, stream>>>(x_in, xr, M * D / 4);
    transpose_all<<<dim3(12288, L), dim3(32, 8), 0, stream>>>(
        Wq, Wk, Wv, Wo, W1, W2, wqkvT, woT, w1T, w2T);

    for (int l = 0; l < L; ++l) {
        const size_t wOff = (size_t)l * D * D;
        const size_t bOff = (size_t)l * D;
        // QKV: 128x256 tiles, BK=32 (2 blocks/CU) -> 768 blocks
        gemm8p<128, 32, 2, 0><<<dim3(768), 512, 0, stream>>>(
            xr, wqkvT + (size_t)l * 3 * D * D, nullptr, nullptr, M, 3 * D, D, 12,
            qb, kb, vtb, bq + bOff, bk + bOff, bv + bOff);
        attn_kernel<<<dim3(B * 16, S / 64), 256, 0, stream>>>(qb, kb, vtb, ob);
        // Wo: 128x256 BK=64 -> 256 blocks
        gemm8p<128, 64, 1, 0><<<dim3(256), 512, 0, stream>>>(
            ob, woT + wOff, bo + bOff, tb, M, D, D, 4,
            nullptr, nullptr, nullptr, nullptr, nullptr, nullptr);
        add_ln<0><<<M, 256, 0, stream>>>(tb, xr, ln1g + bOff, ln1b + bOff, nullptr);
        // FFN1: 256x256 BK=32 (64KB LDS -> 2 blocks/CU TLP, same barrier
        // count per unit K as BK=64/4-phase) -> 512 blocks
        gemm8p<256, 32, 1, 1><<<dim3(512), 512, 0, stream>>>(
            xr, w1T + (size_t)l * D * DFF, b1 + (size_t)l * DFF, hb, M, DFF, D, 16,
            nullptr, nullptr, nullptr, nullptr, nullptr, nullptr);
        // FFN2: 128x256 BK=64 -> 256 blocks
        gemm8p<128, 64, 1, 0><<<dim3(256), 512, 0, stream>>>(
            hb, w2T + (size_t)l * DFF * D, b2 + bOff, tb, M, D, DFF, 4,
            nullptr, nullptr, nullptr, nullptr, nullptr, nullptr);
        if (l == L - 1)
            add_ln<1><<<M, 256, 0, stream>>>(tb, xr, ln2g + bOff, ln2b + bOff, out);
        else
            add_ln<0><<<M, 256, 0, stream>>>(tb, xr, ln2g + bOff, ln2b + bOff, nullptr);
    }
}

// Round 19
// 647.706 us; speedup vs baseline: 1.0082x; 1.0082x over previous
//
#include <hip/hip_runtime.h>

typedef __attribute__((ext_vector_type(8))) short bf16x8;
typedef __attribute__((ext_vector_type(4))) float f32x4;
typedef unsigned short ushort_t;
typedef unsigned int uint32;

#define DEV __device__ __forceinline__
#define SBAR() __builtin_amdgcn_sched_barrier(0)

// round-to-nearest-even f32 -> bf16 (bits)
DEV ushort_t f2bf(float f) {
    uint32 u = __float_as_uint(f);
    uint32 r = (u + 0x7FFFu + ((u >> 16) & 1u)) >> 16;
    return (ushort_t)r;
}
DEV float bf2f(ushort_t h) { return __uint_as_float(((uint32)h) << 16); }

#define MFMA16(a, b, c) __builtin_amdgcn_mfma_f32_16x16x32_bf16((a), (b), (c), 0, 0, 0)

DEV void gload_lds16(const void* g, void* l) {
    __builtin_amdgcn_global_load_lds((const __attribute__((address_space(1))) void*)g,
                                     (__attribute__((address_space(3))) void*)l,
                                     16, 0, 0);
}

// ---------------------------------------------------------------------------
// init: f32 x -> bf16 residual stream xr
// ---------------------------------------------------------------------------
__global__ __launch_bounds__(256) void init_x(const float* __restrict__ xin,
                                              ushort_t* __restrict__ xr, int n4) {
    int i = blockIdx.x * 256 + threadIdx.x;
    if (i >= n4) return;
    float4 v = ((const float4*)xin)[i];
    ushort4 h;
    h.x = f2bf(v.x); h.y = f2bf(v.y); h.z = f2bf(v.z); h.w = f2bf(v.w);
    ((ushort4*)xr)[i] = h;
}

// ---------------------------------------------------------------------------
// all weight transposes in ONE launch: src (K x N f32) -> dst (N x K bf16).
// ---------------------------------------------------------------------------
__global__ __launch_bounds__(256) void transpose_all(const float* __restrict__ Wq,
                                                     const float* __restrict__ Wk,
                                                     const float* __restrict__ Wv,
                                                     const float* __restrict__ Wo,
                                                     const float* __restrict__ W1,
                                                     const float* __restrict__ W2,
                                                     ushort_t* __restrict__ wqkvT,
                                                     ushort_t* __restrict__ woT,
                                                     ushort_t* __restrict__ w1T,
                                                     ushort_t* __restrict__ w2T) {
    const int l = blockIdx.y;
    const int t = blockIdx.x;
    const float* src;
    ushort_t* dst;
    int K, N, ktile, ntile;
    if (t < 4096) {
        const int which = t >> 10, tile = t & 1023;
        K = 1024; N = 1024; ktile = tile >> 5; ntile = tile & 31;
        const size_t o1 = (size_t)l * 1048576;
        if (which == 0)      { src = Wq + o1; dst = wqkvT + (size_t)l * 3145728; }
        else if (which == 1) { src = Wk + o1; dst = wqkvT + (size_t)l * 3145728 + 1048576; }
        else if (which == 2) { src = Wv + o1; dst = wqkvT + (size_t)l * 3145728 + 2097152; }
        else                 { src = Wo + o1; dst = woT + o1; }
    } else if (t < 8192) {
        const int tile = t - 4096;
        K = 1024; N = 4096; ktile = tile >> 7; ntile = tile & 127;
        src = W1 + (size_t)l * 4194304; dst = w1T + (size_t)l * 4194304;
    } else {
        const int tile = t - 8192;
        K = 4096; N = 1024; ktile = tile >> 5; ntile = tile & 31;
        src = W2 + (size_t)l * 4194304; dst = w2T + (size_t)l * 4194304;
    }
    __shared__ float tilebuf[32][33];
    const int tx = threadIdx.x, ty = threadIdx.y;  // (32,8)
    const int nt = ntile * 32, kt = ktile * 32;
#pragma unroll
    for (int j = 0; j < 4; ++j)
        tilebuf[ty + j * 8][tx] = src[(size_t)(kt + ty + j * 8) * N + nt + tx];
    __syncthreads();
#pragma unroll
    for (int j = 0; j < 4; ++j)
        dst[(size_t)(nt + ty + j * 8) * K + kt + tx] = f2bf(tilebuf[tx][ty + j * 8]);
}

// ---------------------------------------------------------------------------
// GEMM: C[M,N] = A[M,K] @ BT[N,K]^T + bias. BM x 256 tile, 8 waves (2M x 4N).
// BK=64: verified r11/r14 schedule (PHASES: BM=256 -> 4, BM=128 -> 2;
//   (mi-half x ks) slicing, counted vmcnt(4) at t+2 depth).
// BK=32 (QKV): 2 phases/K-tile, verified slot discipline (stage A(t+1)@p0 ->
//   nb, B(t+2)@p1 -> cb + vmcnt(2)).
// SESSION CONCLUSION (r10-r18): all correct variants plateau at ~36% MfmaUtil
// — the barrier+lgkm(0) phase structure serializes the LDS pipe (~1200cy of
// ds_read_b128 per K-tile) against the MFMA pipe (~1240cy). Counted-lgkm
// (r13) and merged phases (r16) both raced (stage-write vs lagging-wave-read
// WAR margin ~200cy doesn't survive wider barrier intervals); occupancy/TLP
// (r15 QKV, r18 FFN1 BK=32) and read-balance (r10) are null. Escape requires
// inline-asm producer-consumer K-loop + multi-run race screening.
// MODE: 1 = bf16 out (+RELU), 2 = fused QKV split.
// ---------------------------------------------------------------------------
template <int BM, int BK, int MODE, int RELU>
__global__ __launch_bounds__(512, 2) void gemm8p(const ushort_t* __restrict__ A,
                                                 const ushort_t* __restrict__ BT,
                                                 const float* __restrict__ bias,
                                                 void* __restrict__ Cout,
                                                 int M, int N, int K, int gx,
                                                 ushort_t* __restrict__ qout,
                                                 ushort_t* __restrict__ kout,
                                                 ushort_t* __restrict__ vtout,
                                                 const float* __restrict__ bq,
                                                 const float* __restrict__ bk,
                                                 const float* __restrict__ bv) {
    constexpr int AH = BM / 128;
    constexpr int MREP = BM / 32;
    constexpr int MH = MREP / 2;
    constexpr int PHASES = (BM == 128) ? 2 : 4;   // BK=64 path only
    constexpr int BUFSZ = (BM + 256) * BK;
    constexpr int LDSSZ = (MODE == 2 && 2 * BUFSZ < 32768) ? 32768 : 2 * BUFSZ;
    constexpr int HALF = 128 * BK;                // elems per 128-row half
    __shared__ ushort_t ldsf[LDSSZ];

    // XCD-aware bijective swizzle (m204) + 8-row grouped tile order (gy%8==0)
    const int nwg = gridDim.x;
    const int q8 = nwg >> 3, r8 = nwg & 7;
    const int xcd = blockIdx.x & 7, idx = blockIdx.x >> 3;
    const int swz = (xcd < r8 ? xcd * (q8 + 1) : r8 * (q8 + 1) + (xcd - r8) * q8) + idx;
    const int gchunk = gx * 8;
    const int grp = swz / gchunk, rem = swz % gchunk;
    const int byi = grp * 8 + (rem & 7);
    const int bxi = rem >> 3;

    const int tid = threadIdx.x;
    const int w = tid >> 6, lane = tid & 63;
    const int wr = w >> 2, wc = w & 3;
    const int lr = lane & 15, lh = lane >> 4;
    const int row0 = byi * BM, col0 = bxi * 256;

    f32x4 acc[MREP][4] = {};

    const ushort_t* __restrict__ Ab = A + (size_t)row0 * K;
    const ushort_t* __restrict__ Bb = BT + (size_t)col0 * K;
    const int nt = K / BK;

    // staging geometry
    const int r8l = lane >> 3;                    // BK=64: row-in-8 block
    const int cu64 = (lane & 7) ^ r8l;            // BK=64 swizzled col unit
    const int so64 = w * 1024 + lane * 8;         // BK=64 dest elems
    const int srow32 = tid >> 2;                  // BK=32: row 0..127
    const int cu32 = (tid & 3) ^ ((srow32 >> 1) & 3);  // BK=32 swizzled unit

    const ushort_t* aS[AH][2];
    const ushort_t* bS[2][2];
#pragma unroll
    for (int h2 = 0; h2 < AH; ++h2)
#pragma unroll
        for (int i = 0; i < 2; ++i) {
            if (BK == 64)
                aS[h2][i] = Ab + (size_t)(h2 * 128 + (w * 2 + i) * 8 + r8l) * K + cu64 * 8;
            else
                aS[h2][i] = Ab + (size_t)(h2 * 128 + srow32) * K + cu32 * 8;
        }
#pragma unroll
    for (int h2 = 0; h2 < 2; ++h2)
#pragma unroll
        for (int i = 0; i < 2; ++i) {
            if (BK == 64)
                bS[h2][i] = Bb + (size_t)(h2 * 128 + (w * 2 + i) * 8 + r8l) * K + cu64 * 8;
            else
                bS[h2][i] = Bb + (size_t)(h2 * 128 + srow32) * K + cu32 * 8;
        }

    auto stageA = [&](int buf, int h2) {
        if (BK == 64) {
#pragma unroll
            for (int i = 0; i < 2; ++i) {
                gload_lds16(aS[h2][i], &ldsf[buf * BUFSZ + h2 * HALF + so64 + i * 512]);
                aS[h2][i] += 64;
            }
        } else {
            gload_lds16(aS[h2][0], &ldsf[buf * BUFSZ + h2 * HALF + tid * 8]);
            aS[h2][0] += 32;
        }
    };
    auto stageB = [&](int buf, int h2) {
        if (BK == 64) {
#pragma unroll
            for (int i = 0; i < 2; ++i) {
                gload_lds16(bS[h2][i], &ldsf[buf * BUFSZ + BM * BK + h2 * HALF + so64 + i * 512]);
                bS[h2][i] += 64;
            }
        } else {
            gload_lds16(bS[h2][0], &ldsf[buf * BUFSZ + BM * BK + h2 * HALF + tid * 8]);
            bS[h2][0] += 32;
        }
    };

    int boff[4][2];
#pragma unroll
    for (int ni = 0; ni < 4; ++ni) {
        const int br = wc * 64 + ni * 16 + lr;
        const int rr = br & 127, bh2 = br >> 7;
#pragma unroll
        for (int ks = 0; ks < 2; ++ks) {
            if (BK == 64)
                boff[ni][ks] = BM * 64 + bh2 * HALF + rr * 64 + (((ks * 4 + lh) ^ (rr & 7)) * 8);
            else
                boff[ni][ks] = BM * 32 + bh2 * HALF + rr * 32 + ((lh ^ ((rr >> 1) & 3)) * 8);
        }
    }
    int aoff[MREP][2];
#pragma unroll
    for (int mi = 0; mi < MREP; ++mi) {
        const int fr = wr * (BM / 2) + mi * 16 + lr;
        const int rr = fr & 127, fh = fr >> 7;
#pragma unroll
        for (int ks = 0; ks < 2; ++ks) {
            if (BK == 64)
                aoff[mi][ks] = fh * HALF + rr * 64 + (((ks * 4 + lh) ^ (rr & 7)) * 8);
            else
                aoff[mi][ks] = fh * HALF + rr * 32 + ((lh ^ ((rr >> 1) & 3)) * 8);
        }
    }

    // prologue: tile0 B+A, tile1 B; counted wait completes tile 0
    stageB(0, 0); stageB(0, 1);
    stageA(0, 0); if (AH == 2) stageA(0, 1);
    stageB(1, 0); stageB(1, 1);
    if (BK == 64) asm volatile("s_waitcnt vmcnt(4)" ::: "memory");
    else          asm volatile("s_waitcnt vmcnt(2)" ::: "memory");
    SBAR();
    __builtin_amdgcn_s_barrier();

    for (int t2 = 0; t2 < nt; t2 += 2) {
#pragma unroll
        for (int ti = 0; ti < 2; ++ti) {
            const int t = t2 + ti;
            if (BK == 64) {
                // ------- verified r11/r14 BK=64 path -------
                bf16x8 bfr[2][4];
#pragma unroll
                for (int p = 0; p < PHASES; ++p) {
                    const int ks = p & 1;
                    const int mh = (PHASES == 4) ? (p >> 1) : 0;
                    if (mh == 0) {
#pragma unroll
                        for (int ni = 0; ni < 4; ++ni)
                            bfr[ks][ni] = *(const bf16x8*)&ldsf[ti * BUFSZ + boff[ni][ks]];
                    }
                    bf16x8 af[4];
#pragma unroll
                    for (int mm = 0; mm < 4; ++mm)
                        af[mm] = *(const bf16x8*)&ldsf[ti * BUFSZ + aoff[mh * 4 + mm][ks]];
                    if (PHASES == 4) {
                        if (p == 0) { if (t + 1 < nt) stageA(1 - ti, 0); }
                        else if (p == 1) { if (AH == 2 && t + 1 < nt) stageA(1 - ti, 1); }
                        else if (p == 2) { if (t + 2 < nt) stageB(ti, 0); }
                        else {
                            if (t + 2 < nt) {
                                stageB(ti, 1);
                                asm volatile("s_waitcnt vmcnt(4)" ::: "memory");
                            } else if (t + 1 < nt) {
                                asm volatile("s_waitcnt vmcnt(0)" ::: "memory");
                            }
                        }
                    } else {
                        if (p == 0) { if (t + 1 < nt) stageA(1 - ti, 0); }
                        else {
                            if (t + 2 < nt) {
                                stageB(ti, 0);
                                stageB(ti, 1);
                                asm volatile("s_waitcnt vmcnt(4)" ::: "memory");
                            } else if (t + 1 < nt) {
                                asm volatile("s_waitcnt vmcnt(0)" ::: "memory");
                            }
                        }
                    }
                    SBAR();
                    __builtin_amdgcn_s_barrier();
                    asm volatile("s_waitcnt lgkmcnt(0)" ::: "memory");
                    SBAR();
                    __builtin_amdgcn_s_setprio(1);
#pragma unroll
                    for (int mm = 0; mm < 4; ++mm)
#pragma unroll
                        for (int ni = 0; ni < 4; ++ni)
                            acc[mh * 4 + mm][ni] = MFMA16(af[mm], bfr[ks][ni], acc[mh * 4 + mm][ni]);
                    __builtin_amdgcn_s_setprio(0);
                    SBAR();
                    __builtin_amdgcn_s_barrier();
                }
            } else {
                // ------- BK=32 path (2 phases, verified slot discipline) -------
                bf16x8 bfr[4], af[MREP];
                // p0: read B + A[0..MH-1]; stage A(t+1)->nb
#pragma unroll
                for (int ni = 0; ni < 4; ++ni)
                    bfr[ni] = *(const bf16x8*)&ldsf[ti * BUFSZ + boff[ni][0]];
#pragma unroll
                for (int mi = 0; mi < MH; ++mi)
                    af[mi] = *(const bf16x8*)&ldsf[ti * BUFSZ + aoff[mi][0]];
                if (t + 1 < nt) {
                    stageA(1 - ti, 0);
                    if (AH == 2) stageA(1 - ti, 1);
                }
                SBAR();
                __builtin_amdgcn_s_barrier();
                asm volatile("s_waitcnt lgkmcnt(0)" ::: "memory");
                SBAR();
                __builtin_amdgcn_s_setprio(1);
#pragma unroll
                for (int mi = 0; mi < MH; ++mi)
#pragma unroll
                    for (int ni = 0; ni < 4; ++ni)
                        acc[mi][ni] = MFMA16(af[mi], bfr[ni], acc[mi][ni]);
                __builtin_amdgcn_s_setprio(0);
                SBAR();
                __builtin_amdgcn_s_barrier();
                // p1: read A[MH..]; stage B(t+2)->cb + vmcnt(2)
#pragma unroll
                for (int mi = MH; mi < MREP; ++mi)
                    af[mi] = *(const bf16x8*)&ldsf[ti * BUFSZ + aoff[mi][0]];
                if (t + 2 < nt) {
                    stageB(ti, 0);
                    stageB(ti, 1);
                    asm volatile("s_waitcnt vmcnt(2)" ::: "memory");
                } else if (t + 1 < nt) {
                    asm volatile("s_waitcnt vmcnt(0)" ::: "memory");
                }
                SBAR();
                __builtin_amdgcn_s_barrier();
                asm volatile("s_waitcnt lgkmcnt(0)" ::: "memory");
                SBAR();
                __builtin_amdgcn_s_setprio(1);
#pragma unroll
                for (int mi = MH; mi < MREP; ++mi)
#pragma unroll
                    for (int ni = 0; ni < 4; ++ni)
                        acc[mi][ni] = MFMA16(af[mi], bfr[ni], acc[mi][ni]);
                __builtin_amdgcn_s_setprio(0);
                SBAR();
                __builtin_amdgcn_s_barrier();
            }
        }
    }
    (void)M;

    // ---------------- epilogue ----------------
    if (MODE == 2 && col0 >= 2048) {
        ushort_t* vb = ldsf + w * 4096;
        const int hglob = (col0 - 2048 + wc * 64) >> 6;
        const int bidx = row0 >> 10;
        const int srow0 = (row0 & 1023) + wr * 64;
#pragma unroll
        for (int mi = 0; mi < MREP; ++mi) {
#pragma unroll
            for (int ni = 0; ni < 4; ++ni) {
                const int dd = ni * 16 + lr;
                const float bvv = bv[(hglob << 6) + dd];
                ushort4 h4;
                h4.x = f2bf(acc[mi][ni][0] + bvv);
                h4.y = f2bf(acc[mi][ni][1] + bvv);
                h4.z = f2bf(acc[mi][ni][2] + bvv);
                h4.w = f2bf(acc[mi][ni][3] + bvv);
                const int sb = mi * 32 + lh * 8;
                *(ushort4*)((char*)vb + dd * 128 + (sb ^ ((dd & 3) << 4))) = h4;
            }
        }
        const int ddl = lane >> 3, s8 = lane & 7;
#pragma unroll
        for (int j = 0; j < 8; ++j) {
            const int dd = j * 8 + ddl;
            bf16x8 rowv = *(const bf16x8*)((char*)vb + dd * 128 + ((s8 * 16) ^ ((dd & 3) << 4)));
            *(bf16x8*)&vtout[(((size_t)(bidx * 16 + hglob) * 64 + dd) << 10) + srow0 + s8 * 8] = rowv;
        }
    } else {
#pragma unroll
        for (int mi = 0; mi < MREP; ++mi) {
#pragma unroll
            for (int ni = 0; ni < 4; ++ni) {
                const int col = col0 + wc * 64 + ni * 16 + lr;
                const int rowb = row0 + wr * (BM / 2) + mi * 16 + lh * 4;
                if (MODE == 2) {
                    if (col < 1024) {
                        const float bvv = bq[col];
#pragma unroll
                        for (int r = 0; r < 4; ++r)
                            qout[(size_t)(rowb + r) * 1024 + col] = f2bf((acc[mi][ni][r] + bvv) * 0.125f);
                    } else {
                        const int c = col - 1024;
                        const float bvv = bk[c];
#pragma unroll
                        for (int r = 0; r < 4; ++r)
                            kout[(size_t)(rowb + r) * 1024 + c] = f2bf(acc[mi][ni][r] + bvv);
                    }
                } else {
                    const float bvv = bias[col];
#pragma unroll
                    for (int r = 0; r < 4; ++r) {
                        float val = acc[mi][ni][r] + bvv;
                        if (RELU) val = fmaxf(val, 0.f);
                        ((ushort_t*)Cout)[(size_t)(rowb + r) * N + col] = f2bf(val);
                    }
                }
            }
        }
    }
}

// ---------------------------------------------------------------------------
// fused causal flash attention, KVBLK=128. Grid (bh=128, qt=16).
// ---------------------------------------------------------------------------
__global__ __launch_bounds__(256) void attn_kernel(const ushort_t* __restrict__ q,
                                                   const ushort_t* __restrict__ k,
                                                   const ushort_t* __restrict__ vt,
                                                   ushort_t* __restrict__ o) {
    __shared__ ushort_t ktile[128 * 64];     // 16KB
    __shared__ ushort_t vtile[64 * 128];     // 16KB (dh x 128 keys)
    __shared__ ushort_t p_lds[4][16 * 128];  // 16KB per-wave P

    const int bh = blockIdx.x;
    const int b = bh >> 4, h = bh & 15;
    const int qt = blockIdx.y;
    const int tid = threadIdx.x, w = tid >> 6, lane = tid & 63;
    const int lr = lane & 15, lh = lane >> 4;
    const int qbase = qt * 64 + w * 16;
    const size_t headoff = (size_t)b * 1024 * 1024 + h * 64;
    const size_t vhead = (size_t)(b * 16 + h) << 16;

    bf16x8 qf[2];
#pragma unroll
    for (int ks = 0; ks < 2; ++ks)
        qf[ks] = *(const bf16x8*)&q[headoff + (size_t)(qbase + lr) * 1024 + ks * 32 + lh * 8];

    f32x4 oacc[4] = {};
    float m[4] = {-INFINITY, -INFINITY, -INFINITY, -INFINITY};
    float ls[4] = {0.f, 0.f, 0.f, 0.f};

    const int srow = tid >> 3;
    const int scol8 = (tid & 7) * 8;
    char* const kbase = (char*)ktile;
    char* const vbase = (char*)vtile;
    const int kswzb = (scol8 * 2) ^ ((srow & 7) << 4);
    const int vswzr = ((srow & 15) << 4);
    const ushort_t* kg = k + headoff + (size_t)srow * 1024 + scol8;
    const ushort_t* vg = vt + vhead + (size_t)srow * 1024 + scol8;

    const int jmaxw = qbase + 15;
    const int jend = qt * 64 + 63;

    bf16x8 sk[4], sv[4];
#pragma unroll
    for (int p = 0; p < 4; ++p) sk[p] = *(const bf16x8*)&kg[(size_t)(p * 32) * 1024];
#pragma unroll
    for (int p = 0; p < 2; ++p)
#pragma unroll
        for (int kh = 0; kh < 2; ++kh)
            sv[p * 2 + kh] = *(const bf16x8*)&vg[(size_t)(p * 32) * 1024 + kh * 64];

    for (int j0 = 0; j0 <= jend; j0 += 128) {
        __syncthreads();
#pragma unroll
        for (int p = 0; p < 4; ++p)
            *(bf16x8*)(kbase + (srow + 32 * p) * 128 + kswzb) = sk[p];
#pragma unroll
        for (int p = 0; p < 2; ++p)
#pragma unroll
            for (int kh = 0; kh < 2; ++kh)
                *(bf16x8*)(vbase + (srow + 32 * p) * 256 + ((kh * 128 + scol8 * 2) ^ vswzr)) = sv[p * 2 + kh];
        __syncthreads();
        if (j0 + 128 <= jend) {
#pragma unroll
            for (int p = 0; p < 4; ++p)
                sk[p] = *(const bf16x8*)&kg[(size_t)(j0 + 128 + p * 32) * 1024];
#pragma unroll
            for (int p = 0; p < 2; ++p)
#pragma unroll
                for (int kh = 0; kh < 2; ++kh)
                    sv[p * 2 + kh] = *(const bf16x8*)&vg[(size_t)(p * 32) * 1024 + j0 + 128 + kh * 64];
        }

        if (j0 <= jmaxw) {
            f32x4 s[8] = {};
#pragma unroll
            for (int kt = 0; kt < 8; ++kt) {
                const int krow = kt * 16 + lr;
                const int rswz = ((krow & 7) << 4);
#pragma unroll
                for (int ks = 0; ks < 2; ++ks) {
                    bf16x8 kf = *(const bf16x8*)(kbase + krow * 128 + ((ks * 64 + lh * 16) ^ rswz));
                    s[kt] = MFMA16(qf[ks], kf, s[kt]);
                }
            }
            if (j0 + 127 > qbase) {
#pragma unroll
                for (int kt = 0; kt < 8; ++kt)
#pragma unroll
                    for (int r = 0; r < 4; ++r)
                        s[kt][r] = ((j0 + kt * 16 + lr) <= (qbase + lh * 4 + r)) ? s[kt][r] : -1e9f;
            }
#pragma unroll
            for (int r = 0; r < 4; ++r) {
                float pm = fmaxf(fmaxf(fmaxf(s[0][r], s[1][r]), fmaxf(s[2][r], s[3][r])),
                                 fmaxf(fmaxf(s[4][r], s[5][r]), fmaxf(s[6][r], s[7][r])));
                pm = fmaxf(pm, __shfl_xor(pm, 1, 16));
                pm = fmaxf(pm, __shfl_xor(pm, 2, 16));
                pm = fmaxf(pm, __shfl_xor(pm, 4, 16));
                pm = fmaxf(pm, __shfl_xor(pm, 8, 16));
                const float mn = fmaxf(m[r], pm);
                const float corr = __expf(m[r] - mn);
                m[r] = mn;
                float ps = 0.f;
#pragma unroll
                for (int kt = 0; kt < 8; ++kt) {
                    const float pv = __expf(s[kt][r] - mn);
                    s[kt][r] = pv;
                    ps += pv;
                }
                ps += __shfl_xor(ps, 1, 16);
                ps += __shfl_xor(ps, 2, 16);
                ps += __shfl_xor(ps, 4, 16);
                ps += __shfl_xor(ps, 8, 16);
                ls[r] = ls[r] * corr + ps;
                oacc[0][r] *= corr; oacc[1][r] *= corr;
                oacc[2][r] *= corr; oacc[3][r] *= corr;
            }
            char* const pb = (char*)p_lds[w];
#pragma unroll
            for (int r = 0; r < 4; ++r) {
                const int qrow = lh * 4 + r;
                const int qswz = ((qrow & 15) << 4);
#pragma unroll
                for (int kt = 0; kt < 8; ++kt)
                    *(ushort_t*)(pb + qrow * 256 + ((kt * 32 + lr * 2) ^ qswz)) = f2bf(s[kt][r]);
            }
            const int pswz = ((lr & 15) << 4);
            bf16x8 pa[4];
#pragma unroll
            for (int ks = 0; ks < 4; ++ks)
                pa[ks] = *(const bf16x8*)(pb + lr * 256 + ((ks * 64 + lh * 16) ^ pswz));
#pragma unroll
            for (int dt = 0; dt < 4; ++dt) {
                const int vrow = dt * 16 + lr;
                const int vswz = ((vrow & 15) << 4);
#pragma unroll
                for (int ks = 0; ks < 4; ++ks) {
                    bf16x8 vf = *(const bf16x8*)(vbase + vrow * 256 + ((ks * 64 + lh * 16) ^ vswz));
                    oacc[dt] = MFMA16(pa[ks], vf, oacc[dt]);
                }
            }
        }
    }

    float inv[4];
#pragma unroll
    for (int r = 0; r < 4; ++r) inv[r] = 1.f / ls[r];
#pragma unroll
    for (int dt = 0; dt < 4; ++dt)
#pragma unroll
        for (int r = 0; r < 4; ++r) {
            const int row = qbase + lh * 4 + r;
            o[headoff + (size_t)row * 1024 + dt * 16 + lr] = f2bf(oacc[dt][r] * inv[r]);
        }
}

// ---------------------------------------------------------------------------
// fused residual + LayerNorm on bf16 residual stream: y = LN(t + xr).
// LAST=0: xr <- bf16(y).  LAST=1: out (f32, d_out) <- y.
// ---------------------------------------------------------------------------
template <int LAST>
__global__ __launch_bounds__(256) void add_ln(const ushort_t* __restrict__ t,
                                              ushort_t* __restrict__ xr,
                                              const float* __restrict__ g,
                                              const float* __restrict__ bb,
                                              float* __restrict__ out) {
    const int row = blockIdx.x, tid = threadIdx.x;
    const int lane = tid & 63, w = tid >> 6;
    const size_t base = (size_t)row * 1024;
    ushort4 tv = ((const ushort4*)(t + base))[tid];
    ushort4 xv = ((const ushort4*)(xr + base))[tid];
    float v0 = bf2f(tv.x) + bf2f(xv.x), v1 = bf2f(tv.y) + bf2f(xv.y);
    float v2 = bf2f(tv.z) + bf2f(xv.z), v3 = bf2f(tv.w) + bf2f(xv.w);
    float s = v0 + v1 + v2 + v3;
    float sq = v0 * v0 + v1 * v1 + v2 * v2 + v3 * v3;
#pragma unroll
    for (int off = 32; off >= 1; off >>= 1) {
        s += __shfl_xor(s, off);
        sq += __shfl_xor(sq, off);
    }
    __shared__ float red[8];
    if (lane == 0) { red[w] = s; red[4 + w] = sq; }
    __syncthreads();
    s = red[0] + red[1] + red[2] + red[3];
    sq = red[4] + red[5] + red[6] + red[7];
    const float mu = s * (1.f / 1024.f);
    const float var = sq * (1.f / 1024.f) - mu * mu;
    const float rs = rsqrtf(var + 1e-6f);
    float4 gv = ((const float4*)g)[tid];
    float4 bv = ((const float4*)bb)[tid];
    float y0 = (v0 - mu) * rs * gv.x + bv.x;
    float y1 = (v1 - mu) * rs * gv.y + bv.y;
    float y2 = (v2 - mu) * rs * gv.z + bv.z;
    float y3 = (v3 - mu) * rs * gv.w + bv.w;
    if (LAST) {
        float4 yo; yo.x = y0; yo.y = y1; yo.z = y2; yo.w = y3;
        ((float4*)(out + base))[tid] = yo;
    } else {
        ushort4 hh;
        hh.x = f2bf(y0); hh.y = f2bf(y1); hh.z = f2bf(y2); hh.w = f2bf(y3);
        ((ushort4*)(xr + base))[tid] = hh;
    }
}

// ---------------------------------------------------------------------------
extern "C" void kernel_launch(void* const* d_in, const int* in_sizes, int n_in,
                              void* d_out, int out_size, void* d_ws, size_t ws_size,
                              hipStream_t stream) {
    (void)in_sizes; (void)n_in; (void)out_size; (void)ws_size;
    const int B = 8, S = 1024, D = 1024, DFF = 4096, L = 2;
    const int M = B * S;  // 8192

    const float* x_in = (const float*)d_in[0];
    const float* Wq = (const float*)d_in[2];
    const float* bq = (const float*)d_in[3];
    const float* Wk = (const float*)d_in[4];
    const float* bk = (const float*)d_in[5];
    const float* Wv = (const float*)d_in[6];
    const float* bv = (const float*)d_in[7];
    const float* Wo = (const float*)d_in[8];
    const float* bo = (const float*)d_in[9];
    const float* W1 = (const float*)d_in[10];
    const float* b1 = (const float*)d_in[11];
    const float* W2 = (const float*)d_in[12];
    const float* b2 = (const float*)d_in[13];
    const float* ln1g = (const float*)d_in[14];
    const float* ln1b = (const float*)d_in[15];
    const float* ln2g = (const float*)d_in[16];
    const float* ln2b = (const float*)d_in[17];

    float* out = (float*)d_out;
    char* ws = (char*)d_ws;
    const size_t MB = 1024 * 1024;
    ushort_t* wqkvT = (ushort_t*)(ws + 0 * MB);
    ushort_t* woT = (ushort_t*)(ws + 12 * MB);
    ushort_t* w1T = (ushort_t*)(ws + 16 * MB);
    ushort_t* w2T = (ushort_t*)(ws + 32 * MB);
    ushort_t* xr  = (ushort_t*)(ws + 48 * MB);
    ushort_t* qb  = (ushort_t*)(ws + 64 * MB);
    ushort_t* kb  = (ushort_t*)(ws + 80 * MB);
    ushort_t* vtb = (ushort_t*)(ws + 96 * MB);
    ushort_t* ob  = (ushort_t*)(ws + 112 * MB);
    ushort_t* hb  = (ushort_t*)(ws + 64 * MB);
    ushort_t* tb  = (ushort_t*)(ws + 128 * MB);

    init_x<<<M * D / 4 / 256, 256, 0, stream>>>(x_in, xr, M * D / 4);
    transpose_all<<<dim3(12288, L), dim3(32, 8), 0, stream>>>(
        Wq, Wk, Wv, Wo, W1, W2, wqkvT, woT, w1T, w2T);

    for (int l = 0; l < L; ++l) {
        const size_t wOff = (size_t)l * D * D;
        const size_t bOff = (size_t)l * D;
        // QKV: 128x256 tiles, BK=32 (2 blocks/CU) -> 768 blocks
        gemm8p<128, 32, 2, 0><<<dim3(768), 512, 0, stream>>>(
            xr, wqkvT + (size_t)l * 3 * D * D, nullptr, nullptr, M, 3 * D, D, 12,
            qb, kb, vtb, bq + bOff, bk + bOff, bv + bOff);
        attn_kernel<<<dim3(B * 16, S / 64), 256, 0, stream>>>(qb, kb, vtb, ob);
        // Wo: 128x256 BK=64 -> 256 blocks
        gemm8p<128, 64, 1, 0><<<dim3(256), 512, 0, stream>>>(
            ob, woT + wOff, bo + bOff, tb, M, D, D, 4,
            nullptr, nullptr, nullptr, nullptr, nullptr, nullptr);
        add_ln<0><<<M, 256, 0, stream>>>(tb, xr, ln1g + bOff, ln1b + bOff, nullptr);
        // FFN1: 256x256 BK=64 -> 512 blocks (r17 config: best measured, 651.8us)
        gemm8p<256, 64, 1, 1><<<dim3(512), 512, 0, stream>>>(
            xr, w1T + (size_t)l * D * DFF, b1 + (size_t)l * DFF, hb, M, DFF, D, 16,
            nullptr, nullptr, nullptr, nullptr, nullptr, nullptr);
        // FFN2: 128x256 BK=64 -> 256 blocks
        gemm8p<128, 64, 1, 0><<<dim3(256), 512, 0, stream>>>(
            hb, w2T + (size_t)l * DFF * D, b2 + bOff, tb, M, D, DFF, 4,
            nullptr, nullptr, nullptr, nullptr, nullptr, nullptr);
        if (l == L - 1)
            add_ln<1><<<M, 256, 0, stream>>>(tb, xr, ln2g + bOff, ln2b + bOff, out);
        else
            add_ln<0><<<M, 256, 0, stream>>>(tb, xr, ln2g + bOff, ln2b + bOff, nullptr);
    }
}